// Round 1
// 2164.118 us; speedup vs baseline: 1.3255x; 1.3255x over previous
//
#include <hip/hip_runtime.h>
#include <math.h>

#define NN 100000
#define BB 8
#define SIGMA_C 162.13039087945623f
#define MU_C 117.41975505778706f

// Transposed weights, written once per launch by prep_kernel.
// Layout (floats): w0t[40*40] | w1t[40*20] | w2t[20*20] | w3t[20*20] | w4t[20*10]
// wXt[k*J + j] == wX[j*K + k]  (row = input index k, contiguous in output index j)
__device__ float g_wt[3400];
#define W0T 0
#define W1T 1600
#define W2T 2400
#define W3T 2800
#define W4T 3200

__device__ __forceinline__ float fast_tanh(float v) {
    // tanh(v) = 1 - 2/(1 + e^{2v});  e^{2v} = exp2(v * 2/ln2)
#if __has_builtin(__builtin_amdgcn_exp2f) && __has_builtin(__builtin_amdgcn_rcpf)
    float e = __builtin_amdgcn_exp2f(v * 2.8853900817779268f);
    return 1.0f - 2.0f * __builtin_amdgcn_rcpf(e + 1.0f);
#else
    return tanhf(v);
#endif
}

__global__ void prep_kernel(const float* __restrict__ w0, const float* __restrict__ w1,
                            const float* __restrict__ w2, const float* __restrict__ w3,
                            const float* __restrict__ w4, float* out)
{
    const int t = threadIdx.x;
    if (t < BB) out[t] = MU_C;
    for (int i = t; i < 1600; i += 256) g_wt[W0T + i] = w0[(i % 40) * 40 + (i / 40)];
    for (int i = t; i < 800;  i += 256) g_wt[W1T + i] = w1[(i % 20) * 40 + (i / 20)];
    for (int i = t; i < 400;  i += 256) {
        g_wt[W2T + i] = w2[(i % 20) * 20 + (i / 20)];
        g_wt[W3T + i] = w3[(i % 20) * 20 + (i / 20)];
    }
    for (int i = t; i < 200;  i += 256) g_wt[W4T + i] = w4[(i % 10) * 20 + (i / 10)];
}

__global__ __launch_bounds__(256, 4) void mol_gnn_kernel(
    const float* __restrict__ features,
    const float* __restrict__ nb_connect,
    const float* __restrict__ weights,
    const float* __restrict__ w_scalar,
    const float* __restrict__ b0,
    const float* __restrict__ b1,
    const float* __restrict__ b2,
    const float* __restrict__ b3,
    const float* __restrict__ b4,
    const float* __restrict__ wf,
    const float* __restrict__ bf,
    float* out)
{
    __shared__ float red[BB];
    if (threadIdx.x < BB) red[threadIdx.x] = 0.0f;
    __syncthreads();

    const int tid = blockIdx.x * blockDim.x + threadIdx.x;  // grid covers 800000 exactly
    const int b = tid / NN;
    const int n = tid - b * NN;

    // ---- message-pass coefficients (per node) ----
    const float wv = w_scalar[0];
    float nbc[6];
    #pragma unroll
    for (int i = 0; i < 6; ++i) nbc[i] = nb_connect[n * 6 + i];
    const float nb0 = nbc[0] + nbc[1] + nbc[2];
    const float nb1 = nbc[3] + nbc[4] + nbc[5];
    const float eps = 1e-5f;
    const float nb0s = (nb0 < eps) ? eps : nb0;
    const float nb1s = (nb1 < eps) ? eps : nb1;
    const float h0 = (nb0 > 0.0f) ? 1.0f : 0.0f;
    const float h1 = (nb1 > 0.0f) ? 1.0f : 0.0f;
    float c[7];
    c[0] = 1.0f - h0 * wv - h1 * wv;
    const float i0 = wv / nb0s;
    const float i1 = wv / nb1s;
    c[1] = nbc[0] * i0; c[2] = nbc[1] * i0; c[3] = nbc[2] * i0;
    c[4] = nbc[3] * i1; c[5] = nbc[4] * i1; c[6] = nbc[5] * i1;

    const float* frow = features + ((size_t)b * NN + (size_t)n) * 280;

    float acc[20];
    #pragma unroll
    for (int j = 0; j < 20; ++j) acc[j] = 0.0f;

    // ---- fc0 MLP per s-row, message-pass fused into acc ----
    // k-outer / j-inner: all output accumulators live, input element broadcast.
    // Summation order per output is identical to the previous kernel (bias first,
    // then k ascending), so results match bitwise.
    for (int s = 0; s < 7; ++s) {
        const float4* xv = (const float4*)(frow + s * 40);

        float y[40];
        #pragma unroll
        for (int j = 0; j < 40; ++j) y[j] = b0[j];
        #pragma unroll 2
        for (int kc = 0; kc < 10; ++kc) {
            const float4 v = xv[kc];
            const float* wr = g_wt + W0T + kc * 160;
            #pragma unroll
            for (int j = 0; j < 40; ++j) y[j] += wr[j]       * v.x;
            #pragma unroll
            for (int j = 0; j < 40; ++j) y[j] += wr[40 + j]  * v.y;
            #pragma unroll
            for (int j = 0; j < 40; ++j) y[j] += wr[80 + j]  * v.z;
            #pragma unroll
            for (int j = 0; j < 40; ++j) y[j] += wr[120 + j] * v.w;
        }
        #pragma unroll
        for (int j = 0; j < 40; ++j) y[j] = fast_tanh(y[j]);

        float z[20];
        #pragma unroll
        for (int j = 0; j < 20; ++j) z[j] = b1[j];
        #pragma unroll 4
        for (int k = 0; k < 40; ++k) {
            const float yk = y[k];
            const float* wr = g_wt + W1T + k * 20;
            #pragma unroll
            for (int j = 0; j < 20; ++j) z[j] += wr[j] * yk;
        }
        #pragma unroll
        for (int j = 0; j < 20; ++j) z[j] = fast_tanh(z[j]);

        float t2[20];
        #pragma unroll
        for (int j = 0; j < 20; ++j) t2[j] = b2[j];
        #pragma unroll 4
        for (int k = 0; k < 20; ++k) {
            const float zk = z[k];
            const float* wr = g_wt + W2T + k * 20;
            #pragma unroll
            for (int j = 0; j < 20; ++j) t2[j] += wr[j] * zk;
        }
        const float cs = c[s];
        #pragma unroll
        for (int j = 0; j < 20; ++j) acc[j] += cs * fast_tanh(t2[j]);
    }

    // ---- fc1 + final head (same k-outer structure) ----
    float t1[20];
    #pragma unroll
    for (int j = 0; j < 20; ++j) t1[j] = b3[j];
    #pragma unroll 4
    for (int k = 0; k < 20; ++k) {
        const float ak = acc[k];
        const float* wr = g_wt + W3T + k * 20;
        #pragma unroll
        for (int j = 0; j < 20; ++j) t1[j] += wr[j] * ak;
    }
    #pragma unroll
    for (int j = 0; j < 20; ++j) t1[j] = fast_tanh(t1[j]);

    float t3[10];
    #pragma unroll
    for (int j = 0; j < 10; ++j) t3[j] = b4[j];
    #pragma unroll
    for (int k = 0; k < 20; ++k) {
        const float tk = t1[k];
        const float* wr = g_wt + W4T + k * 10;
        #pragma unroll
        for (int j = 0; j < 10; ++j) t3[j] += wr[j] * tk;
    }
    float e = bf[0];
    #pragma unroll
    for (int j = 0; j < 10; ++j) e += wf[j] * fast_tanh(t3[j]);

    const float contrib = weights[n] * e;

    // ---- per-block reduction, then one global atomic per b present ----
    atomicAdd(&red[b], contrib);
    __syncthreads();
    if (threadIdx.x < BB) {
        float v = red[threadIdx.x];
        if (v != 0.0f) atomicAdd(out + threadIdx.x, v * SIGMA_C);
    }
}

extern "C" void kernel_launch(void* const* d_in, const int* in_sizes, int n_in,
                              void* d_out, int out_size, void* d_ws, size_t ws_size,
                              hipStream_t stream) {
    const float* features   = (const float*)d_in[0];
    const float* nb_connect = (const float*)d_in[1];
    const float* weights    = (const float*)d_in[2];
    const float* w_scalar   = (const float*)d_in[3];
    const float* w0 = (const float*)d_in[4];  const float* b0 = (const float*)d_in[5];
    const float* w1 = (const float*)d_in[6];  const float* b1 = (const float*)d_in[7];
    const float* w2 = (const float*)d_in[8];  const float* b2 = (const float*)d_in[9];
    const float* w3 = (const float*)d_in[10]; const float* b3 = (const float*)d_in[11];
    const float* w4 = (const float*)d_in[12]; const float* b4 = (const float*)d_in[13];
    const float* wf = (const float*)d_in[14]; const float* bf = (const float*)d_in[15];
    float* out = (float*)d_out;

    // prep: init out to MU and build transposed weight tables (13.6 KB device global)
    hipLaunchKernelGGL(prep_kernel, dim3(1), dim3(256), 0, stream, w0, w1, w2, w3, w4, out);

    const int total = BB * NN;             // 800000
    const int block = 256;
    const int grid = (total + block - 1) / block;  // 3125
    hipLaunchKernelGGL(mol_gnn_kernel, dim3(grid), dim3(block), 0, stream,
                       features, nb_connect, weights, w_scalar,
                       b0, b1, b2, b3, b4, wf, bf, out);
}